// Round 5
// baseline (1281.358 us; speedup 1.0000x reference)
//
#include <hip/hip_runtime.h>
#include <hip/hip_bf16.h>
#include <stdint.h>

#define NS_N 100000
#define NE_N 100000
#define MP 100096      // rows padded to multiple of 64 for GEMM blocks
#define EDG_N 1600000
#define DIM 256
#define FEAT_N 64
#define DFF_N 512

using bf16 = __hip_bfloat16;
typedef __bf16 bf16x8 __attribute__((ext_vector_type(8)));
typedef float f32x4 __attribute__((ext_vector_type(4)));

__device__ __forceinline__ float toF(float x) { return x; }
__device__ __forceinline__ float toF(bf16 x) { return __bfloat162float(x); }

template <class T> __device__ __forceinline__ T fromF(float x);
template <> __device__ __forceinline__ float fromF<float>(float x) { return x; }
template <> __device__ __forceinline__ bf16 fromF<bf16>(float x) { return __float2bfloat16(x); }

// async global->LDS, 16B per lane; lds dest must be wave-uniform base (lane*16 implicit)
__device__ __forceinline__ void g2l16(const void* g, void* l) {
    __builtin_amdgcn_global_load_lds((const __attribute__((address_space(1))) unsigned int*)g,
                                     (__attribute__((address_space(3))) unsigned int*)l, 16, 0, 0);
}

// ---- fp32 -> bf16 convert (4-wide), dst row stride S ----
__global__ void cvt_f2b4(const float4* __restrict__ src, bf16* __restrict__ dst,
                         int M, int K4, int S) {
    int idx = blockIdx.x * 256 + threadIdx.x;
    if (idx >= M * K4) return;
    int r = idx / K4, c = (idx - r * K4) * 4;
    float4 v = src[idx];
    union { ushort4 u; bf16 h[4]; } p;
    p.h[0] = fromF<bf16>(v.x); p.h[1] = fromF<bf16>(v.y);
    p.h[2] = fromF<bf16>(v.z); p.h[3] = fromF<bf16>(v.w);
    *(ushort4*)&dst[(size_t)r * S + c] = p.u;
}

// ---- weight transpose fp32 [K][N] -> bf16 [N][K] ----
__global__ void tr_w(const float* __restrict__ src, bf16* __restrict__ dst, int K, int N) {
    int idx = blockIdx.x * 256 + threadIdx.x;
    if (idx >= K * N) return;
    int n = idx / K, k = idx - n * K;
    dst[idx] = fromF<bf16>(src[(size_t)k * N + n]);
}

// ---- per-head weight [8][K][32] -> bf16 [256][K] ----
__global__ void tr_headw(const float* __restrict__ src, bf16* __restrict__ dst, int K) {
    int idx = blockIdx.x * 256 + threadIdx.x;
    if (idx >= 256 * K) return;
    int n = idx / K, k = idx - n * K;
    dst[idx] = fromF<bf16>(src[((size_t)(n >> 5) * K + k) * 32 + (n & 31)]);
}

// ---- CSR build ----
__global__ void count_edges(const int* __restrict__ edst, int* __restrict__ counts) {
    int t = blockIdx.x * 256 + threadIdx.x;
    if (t < EDG_N) atomicAdd(&counts[edst[t]], 1);
}

__global__ void scan_block(const int* __restrict__ counts, int* __restrict__ partial,
                           int* __restrict__ chunk) {
    __shared__ int sh[512];
    int i = blockIdx.x * 512 + threadIdx.x;
    int v = (i < NS_N) ? counts[i] : 0;
    sh[threadIdx.x] = v;
    __syncthreads();
    for (int off = 1; off < 512; off <<= 1) {
        int x = (threadIdx.x >= off) ? sh[threadIdx.x - off] : 0;
        __syncthreads();
        sh[threadIdx.x] += x;
        __syncthreads();
    }
    if (i < NS_N) partial[i] = sh[threadIdx.x] - v;  // exclusive
    if (threadIdx.x == 511) chunk[blockIdx.x] = sh[511];
}

__global__ void scan_chunks(int* __restrict__ chunk, int nc) {
    __shared__ int sh[256];
    int t = threadIdx.x;
    int v = (t < nc) ? chunk[t] : 0;
    sh[t] = v;
    __syncthreads();
    for (int off = 1; off < 256; off <<= 1) {
        int x = (t >= off) ? sh[t - off] : 0;
        __syncthreads();
        sh[t] += x;
        __syncthreads();
    }
    if (t < nc) chunk[t] = sh[t] - v;  // exclusive
}

__global__ void add_offsets(int* __restrict__ rowst, const int* __restrict__ chunk,
                            int* __restrict__ cursor) {
    int i = blockIdx.x * 256 + threadIdx.x;
    if (i < NS_N) {
        int r = rowst[i] + chunk[i >> 9];
        rowst[i] = r;
        cursor[i] = r;
    }
}

__global__ void scatter_edges(const int* __restrict__ esrc, const int* __restrict__ edst,
                              int* __restrict__ cursor, int* __restrict__ csr) {
    int t = blockIdx.x * 256 + threadIdx.x;
    if (t < EDG_N) {
        int d = edst[t];
        int pos = atomicAdd(&cursor[d], 1);
        csr[pos] = esrc[t];
    }
}

// ---- Tall-skinny MFMA GEMM: C[M,N] = epi(A[M,K] @ BT[N,K]^T + bias) (+ res) ----
// Block = BR rows x full N, 4 waves; wave tile = BR rows x 32 cols per pass
// (acc = BR/16 x 2 f32x4 -> 16-32 VGPR, keeps 4+ waves/SIMD resident).
// A-panel (BR x K bf16 = 32KB max) staged to LDS ONCE via global_load_lds with
// 16B-slot XOR swizzle (pre-swizzled global source; same involution on read).
// B (weights, L2-hot) streamed global->reg, 1 k-step prefetch, no barriers in
// the K-loop. MFMA operands SWAPPED (mfma(bfrag, afrag)) so the output
// fragment is transposed: each lane holds 4 consecutive COLS of one row ->
// vector epilogue (float4/ushort4 stores, float4 bias/res loads).
template <int BR, int K, int N, class TC, bool BIAS, bool GELU, bool RES>
__global__ __launch_bounds__(256, 4) void mfma_gemm3(
    const bf16* __restrict__ A, const bf16* __restrict__ BT,
    const float* __restrict__ bias, const float* __restrict__ res,
    TC* __restrict__ C, int M) {
    static_assert(K % 32 == 0 && N % 128 == 0 && (BR == 32 || BR == 64), "shape");
    constexpr int MT = BR / 16;             // row tiles per wave
    constexpr int KS = K / 32;              // k-steps
    constexpr int CHUNKS = BR * K * 2 / 4096;  // 1KB staging chunks per wave
    constexpr int WROWS = BR / 4;           // rows staged per wave
    __shared__ bf16 As[BR * K];

    const int tid = threadIdx.x;
    const int wave = tid >> 6, lane = tid & 63;
    const int m0 = blockIdx.x * BR;

    // ---- stage A once: linear LDS dest, pre-swizzled global source col ----
#pragma unroll
    for (int c = 0; c < CHUNKS; ++c) {
        int off = c * 1024 + lane * 16;          // byte offset within wave's panel
        int riw = off / (K * 2);                 // row within wave's rows
        int slot = (off % (K * 2)) / 16;         // phys 16B slot within row
        int row = wave * WROWS + riw;
        const bf16* g = A + (size_t)(m0 + row) * K + (slot ^ (row & 7)) * 8;
        g2l16(g, As + (size_t)wave * WROWS * K + c * 512);
    }
    __syncthreads();  // one-time vmcnt(0) drain

    const int fr = lane & 15, q = lane >> 4;
    const int f7 = fr & 7;
    const int q4 = q * 4;

    for (int cb0 = 0; cb0 < N; cb0 += 128) {
        const int cb = cb0 + wave * 32;
        f32x4 acc[MT][2];
        const f32x4 zero4 = {0.f, 0.f, 0.f, 0.f};
#pragma unroll
        for (int mt = 0; mt < MT; mt++) {
            acc[mt][0] = zero4;
            acc[mt][1] = zero4;
        }

        const bf16* bp0 = BT + (size_t)(cb + fr) * K;
        const bf16* bp1 = BT + (size_t)(cb + 16 + fr) * K;
        bf16x8 bcur[2];
        bcur[0] = *(const bf16x8*)(bp0 + q * 8);
        bcur[1] = *(const bf16x8*)(bp1 + q * 8);
#pragma unroll
        for (int ks = 0; ks < KS; ++ks) {
            bf16x8 bnxt[2];
            if (ks + 1 < KS) {
                bnxt[0] = *(const bf16x8*)(bp0 + (ks + 1) * 32 + q * 8);
                bnxt[1] = *(const bf16x8*)(bp1 + (ks + 1) * 32 + q * 8);
            }
            const int slot = (ks * 4 + q) ^ f7;  // read-side swizzle
            bf16x8 af[MT];
#pragma unroll
            for (int mt = 0; mt < MT; mt++)
                af[mt] = *(const bf16x8*)(As + (size_t)(mt * 16 + fr) * K + slot * 8);
#pragma unroll
            for (int mt = 0; mt < MT; mt++) {
                // swapped operands: D[i][j], i = B-row (our col), j = A-row (our row)
                acc[mt][0] = __builtin_amdgcn_mfma_f32_16x16x32_bf16(bcur[0], af[mt], acc[mt][0], 0, 0, 0);
                acc[mt][1] = __builtin_amdgcn_mfma_f32_16x16x32_bf16(bcur[1], af[mt], acc[mt][1], 0, 0, 0);
            }
            if (ks + 1 < KS) {
                bcur[0] = bnxt[0];
                bcur[1] = bnxt[1];
            }
        }

        // ---- vector epilogue: lane owns row = m0+mt*16+fr, cols cb+jt*16+q4..+3
#pragma unroll
        for (int jt = 0; jt < 2; jt++) {
            const int col = cb + jt * 16 + q4;
            float4 bv4 = {0.f, 0.f, 0.f, 0.f};
            if (BIAS) bv4 = *(const float4*)&bias[col];
#pragma unroll
            for (int mt = 0; mt < MT; mt++) {
                const int row = m0 + mt * 16 + fr;
                if (row < M) {
                    float v0 = acc[mt][jt][0] + bv4.x;
                    float v1 = acc[mt][jt][1] + bv4.y;
                    float v2 = acc[mt][jt][2] + bv4.z;
                    float v3 = acc[mt][jt][3] + bv4.w;
                    if (RES) {
                        float4 r4 = *(const float4*)&res[(size_t)row * N + col];
                        v0 += r4.x; v1 += r4.y; v2 += r4.z; v3 += r4.w;
                    }
                    if (GELU) {
                        float vv[4] = {v0, v1, v2, v3};
#pragma unroll
                        for (int r = 0; r < 4; r++) {
                            float x = vv[r];
                            float u = 0.7978845608028654f * (x + 0.044715f * x * x * x);
                            float eu = __expf(-2.f * fabsf(u));
                            float th = (1.f - eu) / (1.f + eu);
                            th = (u >= 0.f) ? th : -th;
                            vv[r] = 0.5f * x * (1.f + th);
                        }
                        v0 = vv[0]; v1 = vv[1]; v2 = vv[2]; v3 = vv[3];
                    }
                    if constexpr (sizeof(TC) == 4) {
                        float4 o = {v0, v1, v2, v3};
                        *(float4*)&C[(size_t)row * N + col] = o;
                    } else {
                        union { ushort4 u; bf16 h[4]; } o;
                        o.h[0] = fromF<bf16>(v0);
                        o.h[1] = fromF<bf16>(v1);
                        o.h[2] = fromF<bf16>(v2);
                        o.h[3] = fromF<bf16>(v3);
                        *(ushort4*)&C[(size_t)row * N + col] = o.u;
                    }
                }
            }
        }
    }
}

// ---- fused edge-softmax attention + elu ----
// ONE WAVE per dst (4 waves/block). lane holds 4 channels (bf16x4);
// head = 32ch = 8 lanes -> 3-step butterfly score reduce.
// csr indices prefetched 64-at-a-time into a register, broadcast by shfl.
// 4-edge batched online softmax: 4 gather rows in flight per wave.
__device__ __forceinline__ float4 ldz4(const bf16* __restrict__ p) {
    ushort4 u = *(const ushort4*)p;
    float4 f;
    f.x = toF(*(const bf16*)&u.x);
    f.y = toF(*(const bf16*)&u.y);
    f.z = toF(*(const bf16*)&u.z);
    f.w = toF(*(const bf16*)&u.w);
    return f;
}

__device__ __forceinline__ float dot4(float4 a, float4 b) {
    return fmaf(a.x, b.x, fmaf(a.y, b.y, fmaf(a.z, b.z, a.w * b.w)));
}

__device__ __forceinline__ float hred8(float p) {
    p += __shfl_xor(p, 1);
    p += __shfl_xor(p, 2);
    p += __shfl_xor(p, 4);
    return p;
}

__global__ __launch_bounds__(256) void attn_k(
    const bf16* __restrict__ z, const bf16* __restrict__ df,
    const int* __restrict__ rowst, const int* __restrict__ counts,
    const int* __restrict__ csr, bf16* __restrict__ he) {
    const int dst = blockIdx.x * 4 + (threadIdx.x >> 6);
    if (dst >= NS_N) return;
    const int lane = threadIdx.x & 63;
    const int c4 = lane * 4;  // channel base for this lane

    float4 dfv = ldz4(&df[(size_t)dst * DIM + c4]);

    const int rs = rowst[dst], deg = counts[dst];
    float m = -1e30f, l = 0.f;
    float4 acc = {0.f, 0.f, 0.f, 0.f};

    for (int c0 = 0; c0 < deg; c0 += 64) {
        const int nc = min(64, deg - c0);
        int idx = (lane < nc) ? csr[rs + c0 + lane] : 0;
        int j = 0;
        for (; j + 4 <= nc; j += 4) {
            int s0 = __shfl(idx, j);
            int s1 = __shfl(idx, j + 1);
            int s2 = __shfl(idx, j + 2);
            int s3 = __shfl(idx, j + 3);
            float4 z0 = ldz4(&z[(size_t)s0 * DIM + c4]);
            float4 z1 = ldz4(&z[(size_t)s1 * DIM + c4]);
            float4 z2 = ldz4(&z[(size_t)s2 * DIM + c4]);
            float4 z3 = ldz4(&z[(size_t)s3 * DIM + c4]);
            float p0 = hred8(dot4(z0, dfv));
            float p1 = hred8(dot4(z1, dfv));
            float p2 = hred8(dot4(z2, dfv));
            float p3 = hred8(dot4(z3, dfv));
            float nm = fmaxf(m, fmaxf(fmaxf(p0, p1), fmaxf(p2, p3)));
            float e0 = __expf(m - nm);
            float w0 = __expf(p0 - nm);
            float w1 = __expf(p1 - nm);
            float w2 = __expf(p2 - nm);
            float w3 = __expf(p3 - nm);
            l = fmaf(l, e0, (w0 + w1) + (w2 + w3));
            acc.x = fmaf(acc.x, e0, fmaf(w0, z0.x, fmaf(w1, z1.x, fmaf(w2, z2.x, w3 * z3.x))));
            acc.y = fmaf(acc.y, e0, fmaf(w0, z0.y, fmaf(w1, z1.y, fmaf(w2, z2.y, w3 * z3.y))));
            acc.z = fmaf(acc.z, e0, fmaf(w0, z0.z, fmaf(w1, z1.z, fmaf(w2, z2.z, w3 * z3.z))));
            acc.w = fmaf(acc.w, e0, fmaf(w0, z0.w, fmaf(w1, z1.w, fmaf(w2, z2.w, w3 * z3.w))));
            m = nm;
        }
        for (; j < nc; ++j) {
            int s0 = __shfl(idx, j);
            float4 z0 = ldz4(&z[(size_t)s0 * DIM + c4]);
            float p0 = hred8(dot4(z0, dfv));
            float nm = fmaxf(m, p0);
            float e0 = __expf(m - nm);
            float w0 = __expf(p0 - nm);
            l = fmaf(l, e0, w0);
            acc.x = fmaf(acc.x, e0, w0 * z0.x);
            acc.y = fmaf(acc.y, e0, w0 * z0.y);
            acc.z = fmaf(acc.z, e0, w0 * z0.z);
            acc.w = fmaf(acc.w, e0, w0 * z0.w);
            m = nm;
        }
    }

    const float invl = 1.f / l;
    float hx = acc.x * invl, hy = acc.y * invl, hz = acc.z * invl, hw = acc.w * invl;
    hx = (hx > 0.f) ? hx : expm1f(hx);
    hy = (hy > 0.f) ? hy : expm1f(hy);
    hz = (hz > 0.f) ? hz : expm1f(hz);
    hw = (hw > 0.f) ? hw : expm1f(hw);
    union { ushort4 u; bf16 h[4]; } o;
    o.h[0] = fromF<bf16>(hx);
    o.h[1] = fromF<bf16>(hy);
    o.h[2] = fromF<bf16>(hz);
    o.h[3] = fromF<bf16>(hw);
    *(ushort4*)&he[(size_t)dst * 512 + c4] = o.u;
}

// ---- layernorm over 256, write bf16 ----
__global__ __launch_bounds__(256) void ln_k(const float* __restrict__ h1,
                                            const float* __restrict__ g,
                                            const float* __restrict__ b,
                                            bf16* __restrict__ xn) {
    int row = blockIdx.x, t = threadIdx.x;
    float x = h1[(size_t)row * DIM + t];
    float s1 = x, s2 = x * x;
#pragma unroll
    for (int off = 32; off > 0; off >>= 1) {
        s1 += __shfl_xor(s1, off, 64);
        s2 += __shfl_xor(s2, off, 64);
    }
    __shared__ float red[2][4];
    int w = t >> 6;
    if ((t & 63) == 0) {
        red[0][w] = s1;
        red[1][w] = s2;
    }
    __syncthreads();
    float t1 = red[0][0] + red[0][1] + red[0][2] + red[0][3];
    float t2 = red[1][0] + red[1][1] + red[1][2] + red[1][3];
    float mu = t1 * (1.f / DIM);
    float var = t2 * (1.f / DIM) - mu * mu;
    float v = (x - mu) * rsqrtf(var + 1e-6f) * g[t] + b[t];
    xn[(size_t)row * DIM + t] = fromF<bf16>(v);
}

extern "C" void kernel_launch(void* const* d_in, const int* in_sizes, int n_in,
                              void* d_out, int out_size, void* d_ws, size_t ws_size,
                              hipStream_t stream) {
    const float* s = (const float*)d_in[0];
    const float* e = (const float*)d_in[1];
    const float* dst_feat = (const float*)d_in[2];
    const float* fc_w = (const float*)d_in[3];
    const float* dstfeat_w = (const float*)d_in[4];
    const float* proj_w = (const float*)d_in[5];
    const float* proj_b = (const float*)d_in[6];
    const float* ln_g = (const float*)d_in[7];
    const float* ln_b = (const float*)d_in[8];
    const float* w1 = (const float*)d_in[9];
    const float* b1 = (const float*)d_in[10];
    const float* w2 = (const float*)d_in[11];
    const float* b2 = (const float*)d_in[12];
    const int* edge_src = (const int*)d_in[13];
    const int* edge_dst = (const int*)d_in[14];
    float* out = (float*)d_out;

    char* base = (char*)d_ws;
    size_t off = 0;
    auto alloc = [&](size_t bytes) -> char* {
        char* p = base + off;
        off = (off + bytes + 255) & ~(size_t)255;
        return p;
    };
    // bf16 transposed weights [N][K]
    bf16* fcT = (bf16*)alloc((size_t)256 * 256 * 2);
    bf16* dfeatT = (bf16*)alloc((size_t)256 * 64 * 2);
    bf16* projT = (bf16*)alloc((size_t)256 * 512 * 2);
    bf16* w1T = (bf16*)alloc((size_t)512 * 256 * 2);
    bf16* w2T = (bf16*)alloc((size_t)256 * 512 * 2);
    int* counts = (int*)alloc((size_t)NS_N * 4);
    int* rowst = (int*)alloc((size_t)NS_N * 4);
    int* cursor = (int*)alloc((size_t)NS_N * 4);
    int* chunks = (int*)alloc(1024);
    int* csr = (int*)alloc((size_t)EDG_N * 4);
    bf16* eB = (bf16*)alloc((size_t)MP * DIM * 2);      // 51.2 MB; reused as xnB
    bf16* zB = (bf16*)alloc((size_t)MP * DIM * 2);      // 51.2 MB \ contiguous ->
    bf16* dfB = (bf16*)alloc((size_t)MP * DIM * 2);     // 51.2 MB / a1B (MP x 512)
    bf16* dfeatB = (bf16*)alloc((size_t)MP * FEAT_N * 2);
    bf16* catB = (bf16*)alloc((size_t)MP * 512 * 2);    // [he | s]
    float* h1F = (float*)alloc((size_t)MP * DIM * 4);
    bf16* xnB = eB;   // e dead after gemm1
    bf16* a1B = zB;   // z,df dead after attn; spans zB+dfB = MP*512 bf16

    hipMemsetAsync(counts, 0, (size_t)NS_N * 4, stream);
    // weight prep
    tr_headw<<<(256 * 256 + 255) / 256, 256, 0, stream>>>(fc_w, fcT, 256);
    tr_headw<<<(256 * 64 + 255) / 256, 256, 0, stream>>>(dstfeat_w, dfeatT, 64);
    tr_w<<<(512 * 256 + 255) / 256, 256, 0, stream>>>(proj_w, projT, 512, 256);
    tr_w<<<(256 * 512 + 255) / 256, 256, 0, stream>>>(w1, w1T, 256, 512);
    tr_w<<<(512 * 256 + 255) / 256, 256, 0, stream>>>(w2, w2T, 512, 256);
    // activation converts
    cvt_f2b4<<<(NE_N * 64 + 255) / 256, 256, 0, stream>>>((const float4*)e, eB, NE_N, 64, DIM);
    cvt_f2b4<<<(NS_N * 16 + 255) / 256, 256, 0, stream>>>((const float4*)dst_feat, dfeatB, NS_N, 16, FEAT_N);
    cvt_f2b4<<<(NS_N * 64 + 255) / 256, 256, 0, stream>>>((const float4*)s, catB + 256, NS_N, 64, 512);
    // CSR
    count_edges<<<(EDG_N + 255) / 256, 256, 0, stream>>>(edge_dst, counts);
    int nchunk = (NS_N + 511) / 512;
    scan_block<<<nchunk, 512, 0, stream>>>(counts, rowst, chunks);
    scan_chunks<<<1, 256, 0, stream>>>(chunks, nchunk);
    add_offsets<<<(NS_N + 255) / 256, 256, 0, stream>>>(rowst, chunks, cursor);
    scatter_edges<<<(EDG_N + 255) / 256, 256, 0, stream>>>(edge_src, edge_dst, cursor, csr);

    dim3 blk(256);
    // z = e @ Wz -> bf16
    mfma_gemm3<64, 256, 256, bf16, false, false, false><<<MP / 64, blk, 0, stream>>>(
        eB, fcT, nullptr, nullptr, zB, NE_N);
    // df = dst_feat @ Wd -> bf16
    mfma_gemm3<64, 64, 256, bf16, false, false, false><<<MP / 64, blk, 0, stream>>>(
        dfeatB, dfeatT, nullptr, nullptr, dfB, NS_N);
    // attention -> catB left half (one wave per dst, 4 dsts per block)
    attn_k<<<(NS_N + 3) / 4, 256, 0, stream>>>(zB, dfB, rowst, counts, csr, catB);
    // h1 = cat(he,s) @ proj_w + proj_b -> fp32   (K=512 -> 32-row blocks, 32KB LDS)
    mfma_gemm3<32, 512, 256, float, true, false, false><<<MP / 32, blk, 0, stream>>>(
        catB, projT, proj_b, nullptr, h1F, NS_N);
    // xn = LN(h1) -> bf16
    ln_k<<<NS_N, 256, 0, stream>>>(h1F, ln_g, ln_b, xnB);
    // a1 = gelu(xn @ w1 + b1) -> bf16
    mfma_gemm3<64, 256, 512, bf16, true, true, false><<<MP / 64, blk, 0, stream>>>(
        xnB, w1T, b1, nullptr, a1B, NS_N);
    // out = h1 + (a1 @ w2 + b2) -> fp32
    mfma_gemm3<32, 512, 256, float, true, false, true><<<MP / 32, blk, 0, stream>>>(
        a1B, w2T, b2, h1F, out, NS_N);
}

// Round 6
// 1138.024 us; speedup vs baseline: 1.1259x; 1.1259x over previous
//
#include <hip/hip_runtime.h>
#include <hip/hip_bf16.h>
#include <stdint.h>

#define NS_N 100000
#define NE_N 100000
#define MP 100096      // rows padded to multiple of 64 for GEMM blocks
#define EDG_N 1600000
#define DIM 256
#define FEAT_N 64
#define DFF_N 512

using bf16 = __hip_bfloat16;
typedef __bf16 bf16x8 __attribute__((ext_vector_type(8)));
typedef float f32x4 __attribute__((ext_vector_type(4)));

__device__ __forceinline__ float toF(float x) { return x; }
__device__ __forceinline__ float toF(bf16 x) { return __bfloat162float(x); }

template <class T> __device__ __forceinline__ T fromF(float x);
template <> __device__ __forceinline__ float fromF<float>(float x) { return x; }
template <> __device__ __forceinline__ bf16 fromF<bf16>(float x) { return __float2bfloat16(x); }

// async global->LDS, 16B per lane; lds dest must be wave-uniform base (lane*16 implicit)
__device__ __forceinline__ void g2l16(const void* g, void* l) {
    __builtin_amdgcn_global_load_lds((const __attribute__((address_space(1))) unsigned int*)g,
                                     (__attribute__((address_space(3))) unsigned int*)l, 16, 0, 0);
}

// ---- fp32 -> bf16 convert (4-wide), dst row stride S ----
__global__ void cvt_f2b4(const float4* __restrict__ src, bf16* __restrict__ dst,
                         int M, int K4, int S) {
    int idx = blockIdx.x * 256 + threadIdx.x;
    if (idx >= M * K4) return;
    int r = idx / K4, c = (idx - r * K4) * 4;
    float4 v = src[idx];
    union { ushort4 u; bf16 h[4]; } p;
    p.h[0] = fromF<bf16>(v.x); p.h[1] = fromF<bf16>(v.y);
    p.h[2] = fromF<bf16>(v.z); p.h[3] = fromF<bf16>(v.w);
    *(ushort4*)&dst[(size_t)r * S + c] = p.u;
}

// ---- weight transpose fp32 [K][N] -> bf16 [N][K] ----
__global__ void tr_w(const float* __restrict__ src, bf16* __restrict__ dst, int K, int N) {
    int idx = blockIdx.x * 256 + threadIdx.x;
    if (idx >= K * N) return;
    int n = idx / K, k = idx - n * K;
    dst[idx] = fromF<bf16>(src[(size_t)k * N + n]);
}

// ---- per-head weight [8][K][32] -> bf16 [256][K] ----
__global__ void tr_headw(const float* __restrict__ src, bf16* __restrict__ dst, int K) {
    int idx = blockIdx.x * 256 + threadIdx.x;
    if (idx >= 256 * K) return;
    int n = idx / K, k = idx - n * K;
    dst[idx] = fromF<bf16>(src[((size_t)(n >> 5) * K + k) * 32 + (n & 31)]);
}

// ---- CSR build ----
__global__ void count_edges(const int* __restrict__ edst, int* __restrict__ counts) {
    int t = blockIdx.x * 256 + threadIdx.x;
    if (t < EDG_N) atomicAdd(&counts[edst[t]], 1);
}

__global__ void scan_block(const int* __restrict__ counts, int* __restrict__ partial,
                           int* __restrict__ chunk) {
    __shared__ int sh[512];
    int i = blockIdx.x * 512 + threadIdx.x;
    int v = (i < NS_N) ? counts[i] : 0;
    sh[threadIdx.x] = v;
    __syncthreads();
    for (int off = 1; off < 512; off <<= 1) {
        int x = (threadIdx.x >= off) ? sh[threadIdx.x - off] : 0;
        __syncthreads();
        sh[threadIdx.x] += x;
        __syncthreads();
    }
    if (i < NS_N) partial[i] = sh[threadIdx.x] - v;  // exclusive
    if (threadIdx.x == 511) chunk[blockIdx.x] = sh[511];
}

__global__ void scan_chunks(int* __restrict__ chunk, int nc) {
    __shared__ int sh[256];
    int t = threadIdx.x;
    int v = (t < nc) ? chunk[t] : 0;
    sh[t] = v;
    __syncthreads();
    for (int off = 1; off < 256; off <<= 1) {
        int x = (t >= off) ? sh[t - off] : 0;
        __syncthreads();
        sh[t] += x;
        __syncthreads();
    }
    if (t < nc) chunk[t] = sh[t] - v;  // exclusive
}

__global__ void add_offsets(int* __restrict__ rowst, const int* __restrict__ chunk,
                            int* __restrict__ cursor) {
    int i = blockIdx.x * 256 + threadIdx.x;
    if (i < NS_N) {
        int r = rowst[i] + chunk[i >> 9];
        rowst[i] = r;
        cursor[i] = r;
    }
}

__global__ void scatter_edges(const int* __restrict__ esrc, const int* __restrict__ edst,
                              int* __restrict__ cursor, int* __restrict__ csr) {
    int t = blockIdx.x * 256 + threadIdx.x;
    if (t < EDG_N) {
        int d = edst[t];
        int pos = atomicAdd(&cursor[d], 1);
        csr[pos] = esrc[t];
    }
}

// ---- Tall-skinny MFMA GEMM, burst-register B prefetch ----
// C[M,N] = epi(A[M,K] @ BT[N,K]^T + bias) (+ res)
// Block = BR rows x full N, 4 waves; wave tile = BR rows x 32 cols per pass.
// A-panel (BR x K bf16 = 32KB max) staged to LDS ONCE via global_load_lds
// (16B-slot XOR swizzle, pre-swizzled global source; same involution on read).
// K-loop runs in BURSTS of up to 8 k-steps: all 16 independent B-loads for a
// burst are issued back-to-back (256B/lane in flight -> Little's-law BW), then
// a pure LDS+MFMA inner loop. K=256 GEMMs hold the whole B-slice in regs.
// MFMA operands swapped (mfma(bfrag, afrag)) -> transposed C fragment ->
// vector epilogue (float4/ushort4 stores, float4 bias/res loads).
template <int BR, int K, int N, class TC, bool BIAS, bool GELU, bool RES>
__global__ __launch_bounds__(256, 3) void mfma_gemm4(
    const bf16* __restrict__ A, const bf16* __restrict__ BT,
    const float* __restrict__ bias, const float* __restrict__ res,
    TC* __restrict__ C, int M) {
    static_assert(K % 64 == 0 && N % 128 == 0 && (BR == 32 || BR == 64), "shape");
    constexpr int MT = BR / 16;                // row tiles per wave
    constexpr int KS = K / 32;                 // total k-steps
    constexpr int KB = (KS >= 8) ? 8 : KS;     // k-steps per burst
    constexpr int NBURST = KS / KB;
    constexpr int CHUNKS = BR * K * 2 / 4096;  // 1KB staging chunks per wave
    constexpr int WROWS = BR / 4;              // rows staged per wave
    __shared__ bf16 As[BR * K];

    const int tid = threadIdx.x;
    const int wave = tid >> 6, lane = tid & 63;
    const int m0 = blockIdx.x * BR;

    // ---- stage A once: linear LDS dest, pre-swizzled global source col ----
#pragma unroll
    for (int c = 0; c < CHUNKS; ++c) {
        int off = c * 1024 + lane * 16;          // byte offset within wave's panel
        int riw = off / (K * 2);                 // row within wave's rows
        int slot = (off % (K * 2)) / 16;         // phys 16B slot within row
        int row = wave * WROWS + riw;
        const bf16* g = A + (size_t)(m0 + row) * K + (slot ^ (row & 7)) * 8;
        g2l16(g, As + (size_t)wave * WROWS * K + c * 512);
    }
    __syncthreads();  // one-time vmcnt(0) drain

    const int fr = lane & 15, q = lane >> 4;
    const int f7 = fr & 7;
    const int q4 = q * 4;

    for (int cb0 = 0; cb0 < N; cb0 += 128) {
        const int cb = cb0 + wave * 32;
        f32x4 acc[MT][2];
        const f32x4 zero4 = {0.f, 0.f, 0.f, 0.f};
#pragma unroll
        for (int mt = 0; mt < MT; mt++) {
            acc[mt][0] = zero4;
            acc[mt][1] = zero4;
        }

        const bf16* bp0 = BT + (size_t)(cb + fr) * K + q * 8;
        const bf16* bp1 = BT + (size_t)(cb + 16 + fr) * K + q * 8;

#pragma unroll
        for (int b = 0; b < NBURST; ++b) {
            // ---- burst B-load: 2*KB independent 16B loads, issued together ----
            bf16x8 bfr[KB][2];
#pragma unroll
            for (int ks = 0; ks < KB; ++ks) {
                bfr[ks][0] = *(const bf16x8*)(bp0 + (b * KB + ks) * 32);
                bfr[ks][1] = *(const bf16x8*)(bp1 + (b * KB + ks) * 32);
            }
            // ---- pure LDS+MFMA inner loop ----
#pragma unroll
            for (int ks = 0; ks < KB; ++ks) {
                const int gks = b * KB + ks;
                const int slot = (gks * 4 + q) ^ f7;  // read-side swizzle
                bf16x8 af[MT];
#pragma unroll
                for (int mt = 0; mt < MT; mt++)
                    af[mt] = *(const bf16x8*)(As + (size_t)(mt * 16 + fr) * K + slot * 8);
#pragma unroll
                for (int mt = 0; mt < MT; mt++) {
                    // swapped operands: lane holds row = A-row, 4 consecutive cols
                    acc[mt][0] = __builtin_amdgcn_mfma_f32_16x16x32_bf16(bfr[ks][0], af[mt], acc[mt][0], 0, 0, 0);
                    acc[mt][1] = __builtin_amdgcn_mfma_f32_16x16x32_bf16(bfr[ks][1], af[mt], acc[mt][1], 0, 0, 0);
                }
            }
        }

        // ---- vector epilogue: lane owns row = m0+mt*16+fr, cols cb+jt*16+q4..+3
#pragma unroll
        for (int jt = 0; jt < 2; jt++) {
            const int col = cb + jt * 16 + q4;
            float4 bv4 = {0.f, 0.f, 0.f, 0.f};
            if (BIAS) bv4 = *(const float4*)&bias[col];
#pragma unroll
            for (int mt = 0; mt < MT; mt++) {
                const int row = m0 + mt * 16 + fr;
                if (row < M) {
                    float v0 = acc[mt][jt][0] + bv4.x;
                    float v1 = acc[mt][jt][1] + bv4.y;
                    float v2 = acc[mt][jt][2] + bv4.z;
                    float v3 = acc[mt][jt][3] + bv4.w;
                    if (RES) {
                        float4 r4 = *(const float4*)&res[(size_t)row * N + col];
                        v0 += r4.x; v1 += r4.y; v2 += r4.z; v3 += r4.w;
                    }
                    if (GELU) {
                        float vv[4] = {v0, v1, v2, v3};
#pragma unroll
                        for (int r = 0; r < 4; r++) {
                            float x = vv[r];
                            float u = 0.7978845608028654f * (x + 0.044715f * x * x * x);
                            float eu = __expf(-2.f * fabsf(u));
                            float th = (1.f - eu) / (1.f + eu);
                            th = (u >= 0.f) ? th : -th;
                            vv[r] = 0.5f * x * (1.f + th);
                        }
                        v0 = vv[0]; v1 = vv[1]; v2 = vv[2]; v3 = vv[3];
                    }
                    if constexpr (sizeof(TC) == 4) {
                        float4 o = {v0, v1, v2, v3};
                        *(float4*)&C[(size_t)row * N + col] = o;
                    } else {
                        union { ushort4 u; bf16 h[4]; } o;
                        o.h[0] = fromF<bf16>(v0);
                        o.h[1] = fromF<bf16>(v1);
                        o.h[2] = fromF<bf16>(v2);
                        o.h[3] = fromF<bf16>(v3);
                        *(ushort4*)&C[(size_t)row * N + col] = o.u;
                    }
                }
            }
        }
    }
}

// ---- fused edge-softmax attention + elu ----
// ONE WAVE per dst (4 waves/block). lane holds 4 channels (bf16x4);
// head = 32ch = 8 lanes -> 3-step butterfly score reduce.
// csr indices prefetched 64-at-a-time into a register, broadcast by shfl.
// 4-edge batched online softmax: 4 gather rows in flight per wave.
__device__ __forceinline__ float4 ldz4(const bf16* __restrict__ p) {
    ushort4 u = *(const ushort4*)p;
    float4 f;
    f.x = toF(*(const bf16*)&u.x);
    f.y = toF(*(const bf16*)&u.y);
    f.z = toF(*(const bf16*)&u.z);
    f.w = toF(*(const bf16*)&u.w);
    return f;
}

__device__ __forceinline__ float dot4(float4 a, float4 b) {
    return fmaf(a.x, b.x, fmaf(a.y, b.y, fmaf(a.z, b.z, a.w * b.w)));
}

__device__ __forceinline__ float hred8(float p) {
    p += __shfl_xor(p, 1);
    p += __shfl_xor(p, 2);
    p += __shfl_xor(p, 4);
    return p;
}

__global__ __launch_bounds__(256) void attn_k(
    const bf16* __restrict__ z, const bf16* __restrict__ df,
    const int* __restrict__ rowst, const int* __restrict__ counts,
    const int* __restrict__ csr, bf16* __restrict__ he) {
    const int dst = blockIdx.x * 4 + (threadIdx.x >> 6);
    if (dst >= NS_N) return;
    const int lane = threadIdx.x & 63;
    const int c4 = lane * 4;  // channel base for this lane

    float4 dfv = ldz4(&df[(size_t)dst * DIM + c4]);

    const int rs = rowst[dst], deg = counts[dst];
    float m = -1e30f, l = 0.f;
    float4 acc = {0.f, 0.f, 0.f, 0.f};

    for (int c0 = 0; c0 < deg; c0 += 64) {
        const int nc = min(64, deg - c0);
        int idx = (lane < nc) ? csr[rs + c0 + lane] : 0;
        int j = 0;
        for (; j + 4 <= nc; j += 4) {
            int s0 = __shfl(idx, j);
            int s1 = __shfl(idx, j + 1);
            int s2 = __shfl(idx, j + 2);
            int s3 = __shfl(idx, j + 3);
            float4 z0 = ldz4(&z[(size_t)s0 * DIM + c4]);
            float4 z1 = ldz4(&z[(size_t)s1 * DIM + c4]);
            float4 z2 = ldz4(&z[(size_t)s2 * DIM + c4]);
            float4 z3 = ldz4(&z[(size_t)s3 * DIM + c4]);
            float p0 = hred8(dot4(z0, dfv));
            float p1 = hred8(dot4(z1, dfv));
            float p2 = hred8(dot4(z2, dfv));
            float p3 = hred8(dot4(z3, dfv));
            float nm = fmaxf(m, fmaxf(fmaxf(p0, p1), fmaxf(p2, p3)));
            float e0 = __expf(m - nm);
            float w0 = __expf(p0 - nm);
            float w1 = __expf(p1 - nm);
            float w2 = __expf(p2 - nm);
            float w3 = __expf(p3 - nm);
            l = fmaf(l, e0, (w0 + w1) + (w2 + w3));
            acc.x = fmaf(acc.x, e0, fmaf(w0, z0.x, fmaf(w1, z1.x, fmaf(w2, z2.x, w3 * z3.x))));
            acc.y = fmaf(acc.y, e0, fmaf(w0, z0.y, fmaf(w1, z1.y, fmaf(w2, z2.y, w3 * z3.y))));
            acc.z = fmaf(acc.z, e0, fmaf(w0, z0.z, fmaf(w1, z1.z, fmaf(w2, z2.z, w3 * z3.z))));
            acc.w = fmaf(acc.w, e0, fmaf(w0, z0.w, fmaf(w1, z1.w, fmaf(w2, z2.w, w3 * z3.w))));
            m = nm;
        }
        for (; j < nc; ++j) {
            int s0 = __shfl(idx, j);
            float4 z0 = ldz4(&z[(size_t)s0 * DIM + c4]);
            float p0 = hred8(dot4(z0, dfv));
            float nm = fmaxf(m, p0);
            float e0 = __expf(m - nm);
            float w0 = __expf(p0 - nm);
            l = fmaf(l, e0, w0);
            acc.x = fmaf(acc.x, e0, w0 * z0.x);
            acc.y = fmaf(acc.y, e0, w0 * z0.y);
            acc.z = fmaf(acc.z, e0, w0 * z0.z);
            acc.w = fmaf(acc.w, e0, w0 * z0.w);
            m = nm;
        }
    }

    const float invl = 1.f / l;
    float hx = acc.x * invl, hy = acc.y * invl, hz = acc.z * invl, hw = acc.w * invl;
    hx = (hx > 0.f) ? hx : expm1f(hx);
    hy = (hy > 0.f) ? hy : expm1f(hy);
    hz = (hz > 0.f) ? hz : expm1f(hz);
    hw = (hw > 0.f) ? hw : expm1f(hw);
    union { ushort4 u; bf16 h[4]; } o;
    o.h[0] = fromF<bf16>(hx);
    o.h[1] = fromF<bf16>(hy);
    o.h[2] = fromF<bf16>(hz);
    o.h[3] = fromF<bf16>(hw);
    *(ushort4*)&he[(size_t)dst * 512 + c4] = o.u;
}

// ---- layernorm over 256, write bf16 ----
__global__ __launch_bounds__(256) void ln_k(const float* __restrict__ h1,
                                            const float* __restrict__ g,
                                            const float* __restrict__ b,
                                            bf16* __restrict__ xn) {
    int row = blockIdx.x, t = threadIdx.x;
    float x = h1[(size_t)row * DIM + t];
    float s1 = x, s2 = x * x;
#pragma unroll
    for (int off = 32; off > 0; off >>= 1) {
        s1 += __shfl_xor(s1, off, 64);
        s2 += __shfl_xor(s2, off, 64);
    }
    __shared__ float red[2][4];
    int w = t >> 6;
    if ((t & 63) == 0) {
        red[0][w] = s1;
        red[1][w] = s2;
    }
    __syncthreads();
    float t1 = red[0][0] + red[0][1] + red[0][2] + red[0][3];
    float t2 = red[1][0] + red[1][1] + red[1][2] + red[1][3];
    float mu = t1 * (1.f / DIM);
    float var = t2 * (1.f / DIM) - mu * mu;
    float v = (x - mu) * rsqrtf(var + 1e-6f) * g[t] + b[t];
    xn[(size_t)row * DIM + t] = fromF<bf16>(v);
}

extern "C" void kernel_launch(void* const* d_in, const int* in_sizes, int n_in,
                              void* d_out, int out_size, void* d_ws, size_t ws_size,
                              hipStream_t stream) {
    const float* s = (const float*)d_in[0];
    const float* e = (const float*)d_in[1];
    const float* dst_feat = (const float*)d_in[2];
    const float* fc_w = (const float*)d_in[3];
    const float* dstfeat_w = (const float*)d_in[4];
    const float* proj_w = (const float*)d_in[5];
    const float* proj_b = (const float*)d_in[6];
    const float* ln_g = (const float*)d_in[7];
    const float* ln_b = (const float*)d_in[8];
    const float* w1 = (const float*)d_in[9];
    const float* b1 = (const float*)d_in[10];
    const float* w2 = (const float*)d_in[11];
    const float* b2 = (const float*)d_in[12];
    const int* edge_src = (const int*)d_in[13];
    const int* edge_dst = (const int*)d_in[14];
    float* out = (float*)d_out;

    char* base = (char*)d_ws;
    size_t off = 0;
    auto alloc = [&](size_t bytes) -> char* {
        char* p = base + off;
        off = (off + bytes + 255) & ~(size_t)255;
        return p;
    };
    // bf16 transposed weights [N][K]
    bf16* fcT = (bf16*)alloc((size_t)256 * 256 * 2);
    bf16* dfeatT = (bf16*)alloc((size_t)256 * 64 * 2);
    bf16* projT = (bf16*)alloc((size_t)256 * 512 * 2);
    bf16* w1T = (bf16*)alloc((size_t)512 * 256 * 2);
    bf16* w2T = (bf16*)alloc((size_t)256 * 512 * 2);
    int* counts = (int*)alloc((size_t)NS_N * 4);
    int* rowst = (int*)alloc((size_t)NS_N * 4);
    int* cursor = (int*)alloc((size_t)NS_N * 4);
    int* chunks = (int*)alloc(1024);
    int* csr = (int*)alloc((size_t)EDG_N * 4);
    bf16* eB = (bf16*)alloc((size_t)MP * DIM * 2);      // 51.2 MB; reused as xnB
    bf16* zB = (bf16*)alloc((size_t)MP * DIM * 2);      // 51.2 MB \ contiguous ->
    bf16* dfB = (bf16*)alloc((size_t)MP * DIM * 2);     // 51.2 MB / a1B (MP x 512)
    bf16* dfeatB = (bf16*)alloc((size_t)MP * FEAT_N * 2);
    bf16* catB = (bf16*)alloc((size_t)MP * 512 * 2);    // [he | s]
    float* h1F = (float*)alloc((size_t)MP * DIM * 4);
    bf16* xnB = eB;   // e dead after gemm1
    bf16* a1B = zB;   // z,df dead after attn; spans zB+dfB = MP*512 bf16

    hipMemsetAsync(counts, 0, (size_t)NS_N * 4, stream);
    // weight prep
    tr_headw<<<(256 * 256 + 255) / 256, 256, 0, stream>>>(fc_w, fcT, 256);
    tr_headw<<<(256 * 64 + 255) / 256, 256, 0, stream>>>(dstfeat_w, dfeatT, 64);
    tr_w<<<(512 * 256 + 255) / 256, 256, 0, stream>>>(proj_w, projT, 512, 256);
    tr_w<<<(256 * 512 + 255) / 256, 256, 0, stream>>>(w1, w1T, 256, 512);
    tr_w<<<(512 * 256 + 255) / 256, 256, 0, stream>>>(w2, w2T, 512, 256);
    // activation converts
    cvt_f2b4<<<(NE_N * 64 + 255) / 256, 256, 0, stream>>>((const float4*)e, eB, NE_N, 64, DIM);
    cvt_f2b4<<<(NS_N * 16 + 255) / 256, 256, 0, stream>>>((const float4*)dst_feat, dfeatB, NS_N, 16, FEAT_N);
    cvt_f2b4<<<(NS_N * 64 + 255) / 256, 256, 0, stream>>>((const float4*)s, catB + 256, NS_N, 64, 512);
    // CSR
    count_edges<<<(EDG_N + 255) / 256, 256, 0, stream>>>(edge_dst, counts);
    int nchunk = (NS_N + 511) / 512;
    scan_block<<<nchunk, 512, 0, stream>>>(counts, rowst, chunks);
    scan_chunks<<<1, 256, 0, stream>>>(chunks, nchunk);
    add_offsets<<<(NS_N + 255) / 256, 256, 0, stream>>>(rowst, chunks, cursor);
    scatter_edges<<<(EDG_N + 255) / 256, 256, 0, stream>>>(edge_src, edge_dst, cursor, csr);

    dim3 blk(256);
    // z = e @ Wz -> bf16   (K=256: whole B-slice in regs, 1 burst)
    mfma_gemm4<64, 256, 256, bf16, false, false, false><<<MP / 64, blk, 0, stream>>>(
        eB, fcT, nullptr, nullptr, zB, NE_N);
    // df = dst_feat @ Wd -> bf16
    mfma_gemm4<64, 64, 256, bf16, false, false, false><<<MP / 64, blk, 0, stream>>>(
        dfeatB, dfeatT, nullptr, nullptr, dfB, NS_N);
    // attention -> catB left half (one wave per dst, 4 dsts per block)
    attn_k<<<(NS_N + 3) / 4, 256, 0, stream>>>(zB, dfB, rowst, counts, csr, catB);
    // h1 = cat(he,s) @ proj_w + proj_b -> fp32   (K=512: 2 bursts, 32-row blocks)
    mfma_gemm4<32, 512, 256, float, true, false, false><<<MP / 32, blk, 0, stream>>>(
        catB, projT, proj_b, nullptr, h1F, NS_N);
    // xn = LN(h1) -> bf16
    ln_k<<<NS_N, 256, 0, stream>>>(h1F, ln_g, ln_b, xnB);
    // a1 = gelu(xn @ w1 + b1) -> bf16
    mfma_gemm4<64, 256, 512, bf16, true, true, false><<<MP / 64, blk, 0, stream>>>(
        xnB, w1T, b1, nullptr, a1B, NS_N);
    // out = h1 + (a1 @ w2 + b2) -> fp32
    mfma_gemm4<32, 512, 256, float, true, false, true><<<MP / 32, blk, 0, stream>>>(
        a1B, w2T, b2, h1F, out, NS_N);
}

// Round 7
// 1077.616 us; speedup vs baseline: 1.1891x; 1.0561x over previous
//
#include <hip/hip_runtime.h>
#include <hip/hip_bf16.h>
#include <stdint.h>

#define NS_N 100000
#define NE_N 100000
#define MP 100096      // rows padded to multiple of 64 for GEMM blocks
#define EDG_N 1600000
#define DIM 256
#define FEAT_N 64
#define DFF_N 512

using bf16 = __hip_bfloat16;
typedef __bf16 bf16x8 __attribute__((ext_vector_type(8)));
typedef float f32x4 __attribute__((ext_vector_type(4)));

__device__ __forceinline__ float toF(float x) { return x; }
__device__ __forceinline__ float toF(bf16 x) { return __bfloat162float(x); }

template <class T> __device__ __forceinline__ T fromF(float x);
template <> __device__ __forceinline__ float fromF<float>(float x) { return x; }
template <> __device__ __forceinline__ bf16 fromF<bf16>(float x) { return __float2bfloat16(x); }

// async global->LDS, 16B per lane; lds dest must be wave-uniform base (lane*16 implicit)
__device__ __forceinline__ void g2l16(const void* g, void* l) {
    __builtin_amdgcn_global_load_lds((const __attribute__((address_space(1))) unsigned int*)g,
                                     (__attribute__((address_space(3))) unsigned int*)l, 16, 0, 0);
}

// ---- fp32 -> bf16 convert (4-wide), dst row stride S ----
__global__ void cvt_f2b4(const float4* __restrict__ src, bf16* __restrict__ dst,
                         int M, int K4, int S) {
    int idx = blockIdx.x * 256 + threadIdx.x;
    if (idx >= M * K4) return;
    int r = idx / K4, c = (idx - r * K4) * 4;
    float4 v = src[idx];
    union { ushort4 u; bf16 h[4]; } p;
    p.h[0] = fromF<bf16>(v.x); p.h[1] = fromF<bf16>(v.y);
    p.h[2] = fromF<bf16>(v.z); p.h[3] = fromF<bf16>(v.w);
    *(ushort4*)&dst[(size_t)r * S + c] = p.u;
}

// ---- weight transpose fp32 [K][N] -> bf16 [N][K] ----
__global__ void tr_w(const float* __restrict__ src, bf16* __restrict__ dst, int K, int N) {
    int idx = blockIdx.x * 256 + threadIdx.x;
    if (idx >= K * N) return;
    int n = idx / K, k = idx - n * K;
    dst[idx] = fromF<bf16>(src[(size_t)k * N + n]);
}

// ---- per-head weight [8][K][32] -> bf16 [256][K] ----
__global__ void tr_headw(const float* __restrict__ src, bf16* __restrict__ dst, int K) {
    int idx = blockIdx.x * 256 + threadIdx.x;
    if (idx >= 256 * K) return;
    int n = idx / K, k = idx - n * K;
    dst[idx] = fromF<bf16>(src[((size_t)(n >> 5) * K + k) * 32 + (n & 31)]);
}

// ---- CSR build ----
__global__ void count_edges(const int* __restrict__ edst, int* __restrict__ counts) {
    int t = blockIdx.x * 256 + threadIdx.x;
    if (t < EDG_N) atomicAdd(&counts[edst[t]], 1);
}

__global__ void scan_block(const int* __restrict__ counts, int* __restrict__ partial,
                           int* __restrict__ chunk) {
    __shared__ int sh[512];
    int i = blockIdx.x * 512 + threadIdx.x;
    int v = (i < NS_N) ? counts[i] : 0;
    sh[threadIdx.x] = v;
    __syncthreads();
    for (int off = 1; off < 512; off <<= 1) {
        int x = (threadIdx.x >= off) ? sh[threadIdx.x - off] : 0;
        __syncthreads();
        sh[threadIdx.x] += x;
        __syncthreads();
    }
    if (i < NS_N) partial[i] = sh[threadIdx.x] - v;  // exclusive
    if (threadIdx.x == 511) chunk[blockIdx.x] = sh[511];
}

__global__ void scan_chunks(int* __restrict__ chunk, int nc) {
    __shared__ int sh[256];
    int t = threadIdx.x;
    int v = (t < nc) ? chunk[t] : 0;
    sh[t] = v;
    __syncthreads();
    for (int off = 1; off < 256; off <<= 1) {
        int x = (t >= off) ? sh[t - off] : 0;
        __syncthreads();
        sh[t] += x;
        __syncthreads();
    }
    if (t < nc) chunk[t] = sh[t] - v;  // exclusive
}

__global__ void add_offsets(int* __restrict__ rowst, const int* __restrict__ chunk,
                            int* __restrict__ cursor) {
    int i = blockIdx.x * 256 + threadIdx.x;
    if (i < NS_N) {
        int r = rowst[i] + chunk[i >> 9];
        rowst[i] = r;
        cursor[i] = r;
    }
}

__global__ void scatter_edges(const int* __restrict__ esrc, const int* __restrict__ edst,
                              int* __restrict__ cursor, int* __restrict__ csr) {
    int t = blockIdx.x * 256 + threadIdx.x;
    if (t < EDG_N) {
        int d = edst[t];
        int pos = atomicAdd(&cursor[d], 1);
        csr[pos] = esrc[t];
    }
}

// ---- Tall-skinny MFMA GEMM, PINNED burst-register B prefetch ----
// C[M,N] = epi(A[M,K] @ BT[N,K]^T + bias) (+ res)
// Block = BR rows x full N, 4 waves; wave tile = BR rows x 32 cols per pass.
// A-panel staged to LDS once (XOR-swizzled; pre-swizzled global source).
// B streamed in bursts of KB=4 k-steps (8x16B independent loads). Bursts are
// PINNED with sched_barrier(0) fences so the scheduler cannot sink the loads
// (round-5 failure: VGPR=44 proved loads were sunk to depth-1). Ping-pong
// register sets (bufA/bufB, all static indices) pipeline one burst ahead:
// load(b+1) issued before compute(b), fenced on both sides.
template <int BR, int K, int N, class TC, bool BIAS, bool GELU, bool RES>
__global__ __launch_bounds__(256, 3) void mfma_gemm5(
    const bf16* __restrict__ A, const bf16* __restrict__ BT,
    const float* __restrict__ bias, const float* __restrict__ res,
    TC* __restrict__ C, int M) {
    static_assert(K % 64 == 0 && N % 128 == 0 && (BR == 32 || BR == 64), "shape");
    constexpr int MT = BR / 16;                // row tiles per wave
    constexpr int KS = K / 32;                 // total k-steps
    constexpr int KB = (KS >= 4) ? 4 : KS;     // k-steps per burst
    constexpr int NBURST = KS / KB;            // 1, 2 or 4 (even or 1)
    constexpr int CHUNKS = BR * K * 2 / 4096;  // 1KB staging chunks per wave
    constexpr int WROWS = BR / 4;              // rows staged per wave
    __shared__ bf16 As[BR * K];

    const int tid = threadIdx.x;
    const int wave = tid >> 6, lane = tid & 63;
    const int m0 = blockIdx.x * BR;

    // ---- stage A once: linear LDS dest, pre-swizzled global source col ----
#pragma unroll
    for (int c = 0; c < CHUNKS; ++c) {
        int off = c * 1024 + lane * 16;          // byte offset within wave's panel
        int riw = off / (K * 2);                 // row within wave's rows
        int slot = (off % (K * 2)) / 16;         // phys 16B slot within row
        int row = wave * WROWS + riw;
        const bf16* g = A + (size_t)(m0 + row) * K + (slot ^ (row & 7)) * 8;
        g2l16(g, As + (size_t)wave * WROWS * K + c * 512);
    }
    __syncthreads();  // one-time vmcnt(0) drain

    const int fr = lane & 15, q = lane >> 4;
    const int f7 = fr & 7;
    const int q4 = q * 4;

    for (int cb0 = 0; cb0 < N; cb0 += 128) {
        const int cb = cb0 + wave * 32;
        f32x4 acc[MT][2];
        const f32x4 zero4 = {0.f, 0.f, 0.f, 0.f};
#pragma unroll
        for (int mt = 0; mt < MT; mt++) {
            acc[mt][0] = zero4;
            acc[mt][1] = zero4;
        }

        const bf16* bp0 = BT + (size_t)(cb + fr) * K + q * 8;
        const bf16* bp1 = BT + (size_t)(cb + 16 + fr) * K + q * 8;

        bf16x8 bufA[KB][2], bufB[KB][2];

        auto LOADB = [&](bf16x8 (&dst)[KB][2], int b) {
#pragma unroll
            for (int ks = 0; ks < KB; ++ks) {
                dst[ks][0] = *(const bf16x8*)(bp0 + (b * KB + ks) * 32);
                dst[ks][1] = *(const bf16x8*)(bp1 + (b * KB + ks) * 32);
            }
        };
        auto COMPUTE = [&](bf16x8 (&src)[KB][2], int b) {
#pragma unroll
            for (int ks = 0; ks < KB; ++ks) {
                const int gks = b * KB + ks;
                const int slot = (gks * 4 + q) ^ f7;  // read-side swizzle
                bf16x8 af[MT];
#pragma unroll
                for (int mt = 0; mt < MT; mt++)
                    af[mt] = *(const bf16x8*)(As + (size_t)(mt * 16 + fr) * K + slot * 8);
#pragma unroll
                for (int mt = 0; mt < MT; mt++) {
                    // swapped operands: lane holds row = A-row, 4 consecutive cols
                    acc[mt][0] = __builtin_amdgcn_mfma_f32_16x16x32_bf16(src[ks][0], af[mt], acc[mt][0], 0, 0, 0);
                    acc[mt][1] = __builtin_amdgcn_mfma_f32_16x16x32_bf16(src[ks][1], af[mt], acc[mt][1], 0, 0, 0);
                }
            }
        };

        LOADB(bufA, 0);
#pragma unroll
        for (int b = 0; b < NBURST; b += 2) {
            __builtin_amdgcn_sched_barrier(0);
            if (b + 1 < NBURST) LOADB(bufB, b + 1);
            __builtin_amdgcn_sched_barrier(0);
            COMPUTE(bufA, b);
            __builtin_amdgcn_sched_barrier(0);
            if (b + 2 < NBURST) LOADB(bufA, b + 2);
            __builtin_amdgcn_sched_barrier(0);
            if (b + 1 < NBURST) COMPUTE(bufB, b + 1);
        }

        // ---- vector epilogue: lane owns row = m0+mt*16+fr, cols cb+jt*16+q4..+3
#pragma unroll
        for (int jt = 0; jt < 2; jt++) {
            const int col = cb + jt * 16 + q4;
            float4 bv4 = {0.f, 0.f, 0.f, 0.f};
            if (BIAS) bv4 = *(const float4*)&bias[col];
#pragma unroll
            for (int mt = 0; mt < MT; mt++) {
                const int row = m0 + mt * 16 + fr;
                if (row < M) {
                    float v0 = acc[mt][jt][0] + bv4.x;
                    float v1 = acc[mt][jt][1] + bv4.y;
                    float v2 = acc[mt][jt][2] + bv4.z;
                    float v3 = acc[mt][jt][3] + bv4.w;
                    if (RES) {
                        float4 r4 = *(const float4*)&res[(size_t)row * N + col];
                        v0 += r4.x; v1 += r4.y; v2 += r4.z; v3 += r4.w;
                    }
                    if (GELU) {
                        float vv[4] = {v0, v1, v2, v3};
#pragma unroll
                        for (int r = 0; r < 4; r++) {
                            float x = vv[r];
                            float u = 0.7978845608028654f * (x + 0.044715f * x * x * x);
                            float eu = __expf(-2.f * fabsf(u));
                            float th = (1.f - eu) / (1.f + eu);
                            th = (u >= 0.f) ? th : -th;
                            vv[r] = 0.5f * x * (1.f + th);
                        }
                        v0 = vv[0]; v1 = vv[1]; v2 = vv[2]; v3 = vv[3];
                    }
                    if constexpr (sizeof(TC) == 4) {
                        float4 o = {v0, v1, v2, v3};
                        *(float4*)&C[(size_t)row * N + col] = o;
                    } else {
                        union { ushort4 u; bf16 h[4]; } o;
                        o.h[0] = fromF<bf16>(v0);
                        o.h[1] = fromF<bf16>(v1);
                        o.h[2] = fromF<bf16>(v2);
                        o.h[3] = fromF<bf16>(v3);
                        *(ushort4*)&C[(size_t)row * N + col] = o.u;
                    }
                }
            }
        }
    }
}

// ---- fused edge-softmax attention + elu ----
// ONE WAVE per dst (4 waves/block). lane holds 4 channels (bf16x4);
// head = 32ch = 8 lanes -> 3-step butterfly score reduce.
// csr indices prefetched 64-at-a-time into a register, broadcast by shfl.
// 4-edge batched online softmax: 4 gather rows in flight per wave.
__device__ __forceinline__ float4 ldz4(const bf16* __restrict__ p) {
    ushort4 u = *(const ushort4*)p;
    float4 f;
    f.x = toF(*(const bf16*)&u.x);
    f.y = toF(*(const bf16*)&u.y);
    f.z = toF(*(const bf16*)&u.z);
    f.w = toF(*(const bf16*)&u.w);
    return f;
}

__device__ __forceinline__ float dot4(float4 a, float4 b) {
    return fmaf(a.x, b.x, fmaf(a.y, b.y, fmaf(a.z, b.z, a.w * b.w)));
}

__device__ __forceinline__ float hred8(float p) {
    p += __shfl_xor(p, 1);
    p += __shfl_xor(p, 2);
    p += __shfl_xor(p, 4);
    return p;
}

__global__ __launch_bounds__(256) void attn_k(
    const bf16* __restrict__ z, const bf16* __restrict__ df,
    const int* __restrict__ rowst, const int* __restrict__ counts,
    const int* __restrict__ csr, bf16* __restrict__ he) {
    const int dst = blockIdx.x * 4 + (threadIdx.x >> 6);
    if (dst >= NS_N) return;
    const int lane = threadIdx.x & 63;
    const int c4 = lane * 4;  // channel base for this lane

    float4 dfv = ldz4(&df[(size_t)dst * DIM + c4]);

    const int rs = rowst[dst], deg = counts[dst];
    float m = -1e30f, l = 0.f;
    float4 acc = {0.f, 0.f, 0.f, 0.f};

    for (int c0 = 0; c0 < deg; c0 += 64) {
        const int nc = min(64, deg - c0);
        int idx = (lane < nc) ? csr[rs + c0 + lane] : 0;
        int j = 0;
        for (; j + 4 <= nc; j += 4) {
            int s0 = __shfl(idx, j);
            int s1 = __shfl(idx, j + 1);
            int s2 = __shfl(idx, j + 2);
            int s3 = __shfl(idx, j + 3);
            float4 z0 = ldz4(&z[(size_t)s0 * DIM + c4]);
            float4 z1 = ldz4(&z[(size_t)s1 * DIM + c4]);
            float4 z2 = ldz4(&z[(size_t)s2 * DIM + c4]);
            float4 z3 = ldz4(&z[(size_t)s3 * DIM + c4]);
            float p0 = hred8(dot4(z0, dfv));
            float p1 = hred8(dot4(z1, dfv));
            float p2 = hred8(dot4(z2, dfv));
            float p3 = hred8(dot4(z3, dfv));
            float nm = fmaxf(m, fmaxf(fmaxf(p0, p1), fmaxf(p2, p3)));
            float e0 = __expf(m - nm);
            float w0 = __expf(p0 - nm);
            float w1 = __expf(p1 - nm);
            float w2 = __expf(p2 - nm);
            float w3 = __expf(p3 - nm);
            l = fmaf(l, e0, (w0 + w1) + (w2 + w3));
            acc.x = fmaf(acc.x, e0, fmaf(w0, z0.x, fmaf(w1, z1.x, fmaf(w2, z2.x, w3 * z3.x))));
            acc.y = fmaf(acc.y, e0, fmaf(w0, z0.y, fmaf(w1, z1.y, fmaf(w2, z2.y, w3 * z3.y))));
            acc.z = fmaf(acc.z, e0, fmaf(w0, z0.z, fmaf(w1, z1.z, fmaf(w2, z2.z, w3 * z3.z))));
            acc.w = fmaf(acc.w, e0, fmaf(w0, z0.w, fmaf(w1, z1.w, fmaf(w2, z2.w, w3 * z3.w))));
            m = nm;
        }
        for (; j < nc; ++j) {
            int s0 = __shfl(idx, j);
            float4 z0 = ldz4(&z[(size_t)s0 * DIM + c4]);
            float p0 = hred8(dot4(z0, dfv));
            float nm = fmaxf(m, p0);
            float e0 = __expf(m - nm);
            float w0 = __expf(p0 - nm);
            l = fmaf(l, e0, w0);
            acc.x = fmaf(acc.x, e0, w0 * z0.x);
            acc.y = fmaf(acc.y, e0, w0 * z0.y);
            acc.z = fmaf(acc.z, e0, w0 * z0.z);
            acc.w = fmaf(acc.w, e0, w0 * z0.w);
            m = nm;
        }
    }

    const float invl = 1.f / l;
    float hx = acc.x * invl, hy = acc.y * invl, hz = acc.z * invl, hw = acc.w * invl;
    hx = (hx > 0.f) ? hx : expm1f(hx);
    hy = (hy > 0.f) ? hy : expm1f(hy);
    hz = (hz > 0.f) ? hz : expm1f(hz);
    hw = (hw > 0.f) ? hw : expm1f(hw);
    union { ushort4 u; bf16 h[4]; } o;
    o.h[0] = fromF<bf16>(hx);
    o.h[1] = fromF<bf16>(hy);
    o.h[2] = fromF<bf16>(hz);
    o.h[3] = fromF<bf16>(hw);
    *(ushort4*)&he[(size_t)dst * 512 + c4] = o.u;
}

// ---- layernorm over 256, write bf16 ----
__global__ __launch_bounds__(256) void ln_k(const float* __restrict__ h1,
                                            const float* __restrict__ g,
                                            const float* __restrict__ b,
                                            bf16* __restrict__ xn) {
    int row = blockIdx.x, t = threadIdx.x;
    float x = h1[(size_t)row * DIM + t];
    float s1 = x, s2 = x * x;
#pragma unroll
    for (int off = 32; off > 0; off >>= 1) {
        s1 += __shfl_xor(s1, off, 64);
        s2 += __shfl_xor(s2, off, 64);
    }
    __shared__ float red[2][4];
    int w = t >> 6;
    if ((t & 63) == 0) {
        red[0][w] = s1;
        red[1][w] = s2;
    }
    __syncthreads();
    float t1 = red[0][0] + red[0][1] + red[0][2] + red[0][3];
    float t2 = red[1][0] + red[1][1] + red[1][2] + red[1][3];
    float mu = t1 * (1.f / DIM);
    float var = t2 * (1.f / DIM) - mu * mu;
    float v = (x - mu) * rsqrtf(var + 1e-6f) * g[t] + b[t];
    xn[(size_t)row * DIM + t] = fromF<bf16>(v);
}

extern "C" void kernel_launch(void* const* d_in, const int* in_sizes, int n_in,
                              void* d_out, int out_size, void* d_ws, size_t ws_size,
                              hipStream_t stream) {
    const float* s = (const float*)d_in[0];
    const float* e = (const float*)d_in[1];
    const float* dst_feat = (const float*)d_in[2];
    const float* fc_w = (const float*)d_in[3];
    const float* dstfeat_w = (const float*)d_in[4];
    const float* proj_w = (const float*)d_in[5];
    const float* proj_b = (const float*)d_in[6];
    const float* ln_g = (const float*)d_in[7];
    const float* ln_b = (const float*)d_in[8];
    const float* w1 = (const float*)d_in[9];
    const float* b1 = (const float*)d_in[10];
    const float* w2 = (const float*)d_in[11];
    const float* b2 = (const float*)d_in[12];
    const int* edge_src = (const int*)d_in[13];
    const int* edge_dst = (const int*)d_in[14];
    float* out = (float*)d_out;

    char* base = (char*)d_ws;
    size_t off = 0;
    auto alloc = [&](size_t bytes) -> char* {
        char* p = base + off;
        off = (off + bytes + 255) & ~(size_t)255;
        return p;
    };
    // bf16 transposed weights [N][K]
    bf16* fcT = (bf16*)alloc((size_t)256 * 256 * 2);
    bf16* dfeatT = (bf16*)alloc((size_t)256 * 64 * 2);
    bf16* projT = (bf16*)alloc((size_t)256 * 512 * 2);
    bf16* w1T = (bf16*)alloc((size_t)512 * 256 * 2);
    bf16* w2T = (bf16*)alloc((size_t)256 * 512 * 2);
    int* counts = (int*)alloc((size_t)NS_N * 4);
    int* rowst = (int*)alloc((size_t)NS_N * 4);
    int* cursor = (int*)alloc((size_t)NS_N * 4);
    int* chunks = (int*)alloc(1024);
    int* csr = (int*)alloc((size_t)EDG_N * 4);
    bf16* eB = (bf16*)alloc((size_t)MP * DIM * 2);      // 51.2 MB; reused as xnB
    bf16* zB = (bf16*)alloc((size_t)MP * DIM * 2);      // 51.2 MB \ contiguous ->
    bf16* dfB = (bf16*)alloc((size_t)MP * DIM * 2);     // 51.2 MB / a1B (MP x 512)
    bf16* dfeatB = (bf16*)alloc((size_t)MP * FEAT_N * 2);
    bf16* catB = (bf16*)alloc((size_t)MP * 512 * 2);    // [he | s]
    float* h1F = (float*)alloc((size_t)MP * DIM * 4);
    bf16* xnB = eB;   // e dead after gemm1
    bf16* a1B = zB;   // z,df dead after attn; spans zB+dfB = MP*512 bf16

    hipMemsetAsync(counts, 0, (size_t)NS_N * 4, stream);
    // weight prep
    tr_headw<<<(256 * 256 + 255) / 256, 256, 0, stream>>>(fc_w, fcT, 256);
    tr_headw<<<(256 * 64 + 255) / 256, 256, 0, stream>>>(dstfeat_w, dfeatT, 64);
    tr_w<<<(512 * 256 + 255) / 256, 256, 0, stream>>>(proj_w, projT, 512, 256);
    tr_w<<<(256 * 512 + 255) / 256, 256, 0, stream>>>(w1, w1T, 256, 512);
    tr_w<<<(512 * 256 + 255) / 256, 256, 0, stream>>>(w2, w2T, 512, 256);
    // activation converts
    cvt_f2b4<<<(NE_N * 64 + 255) / 256, 256, 0, stream>>>((const float4*)e, eB, NE_N, 64, DIM);
    cvt_f2b4<<<(NS_N * 16 + 255) / 256, 256, 0, stream>>>((const float4*)dst_feat, dfeatB, NS_N, 16, FEAT_N);
    cvt_f2b4<<<(NS_N * 64 + 255) / 256, 256, 0, stream>>>((const float4*)s, catB + 256, NS_N, 64, 512);
    // CSR
    count_edges<<<(EDG_N + 255) / 256, 256, 0, stream>>>(edge_dst, counts);
    int nchunk = (NS_N + 511) / 512;
    scan_block<<<nchunk, 512, 0, stream>>>(counts, rowst, chunks);
    scan_chunks<<<1, 256, 0, stream>>>(chunks, nchunk);
    add_offsets<<<(NS_N + 255) / 256, 256, 0, stream>>>(rowst, chunks, cursor);
    scatter_edges<<<(EDG_N + 255) / 256, 256, 0, stream>>>(edge_src, edge_dst, cursor, csr);

    dim3 blk(256);
    // z = e @ Wz -> bf16   (K=256: 2 bursts)
    mfma_gemm5<64, 256, 256, bf16, false, false, false><<<MP / 64, blk, 0, stream>>>(
        eB, fcT, nullptr, nullptr, zB, NE_N);
    // df = dst_feat @ Wd -> bf16  (K=64: 1 burst)
    mfma_gemm5<64, 64, 256, bf16, false, false, false><<<MP / 64, blk, 0, stream>>>(
        dfeatB, dfeatT, nullptr, nullptr, dfB, NS_N);
    // attention -> catB left half (one wave per dst, 4 dsts per block)
    attn_k<<<(NS_N + 3) / 4, 256, 0, stream>>>(zB, dfB, rowst, counts, csr, catB);
    // h1 = cat(he,s) @ proj_w + proj_b -> fp32   (K=512: 4 bursts, 32-row blocks)
    mfma_gemm5<32, 512, 256, float, true, false, false><<<MP / 32, blk, 0, stream>>>(
        catB, projT, proj_b, nullptr, h1F, NS_N);
    // xn = LN(h1) -> bf16
    ln_k<<<NS_N, 256, 0, stream>>>(h1F, ln_g, ln_b, xnB);
    // a1 = gelu(xn @ w1 + b1) -> bf16
    mfma_gemm5<64, 256, 512, bf16, true, true, false><<<MP / 64, blk, 0, stream>>>(
        xnB, w1T, b1, nullptr, a1B, NS_N);
    // out = h1 + (a1 @ w2 + b2) -> fp32
    mfma_gemm5<32, 512, 256, float, true, false, true><<<MP / 32, blk, 0, stream>>>(
        a1B, w2T, b2, h1F, out, NS_N);
}

// Round 8
// 970.767 us; speedup vs baseline: 1.3199x; 1.1101x over previous
//
#include <hip/hip_runtime.h>
#include <hip/hip_bf16.h>
#include <stdint.h>

#define NS_N 100000
#define NE_N 100000
#define MP 100096      // rows padded to multiple of 64 for GEMM chunks
#define EDG_N 1600000
#define DIM 256
#define FEAT_N 64
#define DFF_N 512

using bf16 = __hip_bfloat16;
typedef __bf16 bf16x8 __attribute__((ext_vector_type(8)));
typedef float f32x4 __attribute__((ext_vector_type(4)));

__device__ __forceinline__ float toF(float x) { return x; }
__device__ __forceinline__ float toF(bf16 x) { return __bfloat162float(x); }

template <class T> __device__ __forceinline__ T fromF(float x);
template <> __device__ __forceinline__ float fromF<float>(float x) { return x; }
template <> __device__ __forceinline__ bf16 fromF<bf16>(float x) { return __float2bfloat16(x); }

// async global->LDS, 16B per lane; lds dest must be wave-uniform base (lane*16 implicit)
__device__ __forceinline__ void g2l16(const void* g, void* l) {
    __builtin_amdgcn_global_load_lds((const __attribute__((address_space(1))) unsigned int*)g,
                                     (__attribute__((address_space(3))) unsigned int*)l, 16, 0, 0);
}

// ---- fp32 -> bf16 convert (4-wide), dst row stride S ----
__global__ void cvt_f2b4(const float4* __restrict__ src, bf16* __restrict__ dst,
                         int M, int K4, int S) {
    int idx = blockIdx.x * 256 + threadIdx.x;
    if (idx >= M * K4) return;
    int r = idx / K4, c = (idx - r * K4) * 4;
    float4 v = src[idx];
    union { ushort4 u; bf16 h[4]; } p;
    p.h[0] = fromF<bf16>(v.x); p.h[1] = fromF<bf16>(v.y);
    p.h[2] = fromF<bf16>(v.z); p.h[3] = fromF<bf16>(v.w);
    *(ushort4*)&dst[(size_t)r * S + c] = p.u;
}

// ---- weight transpose fp32 [K][N] -> bf16 [N][K] ----
__global__ void tr_w(const float* __restrict__ src, bf16* __restrict__ dst, int K, int N) {
    int idx = blockIdx.x * 256 + threadIdx.x;
    if (idx >= K * N) return;
    int n = idx / K, k = idx - n * K;
    dst[idx] = fromF<bf16>(src[(size_t)k * N + n]);
}

// ---- per-head weight [8][K][32] -> bf16 [256][K] ----
__global__ void tr_headw(const float* __restrict__ src, bf16* __restrict__ dst, int K) {
    int idx = blockIdx.x * 256 + threadIdx.x;
    if (idx >= 256 * K) return;
    int n = idx / K, k = idx - n * K;
    dst[idx] = fromF<bf16>(src[((size_t)(n >> 5) * K + k) * 32 + (n & 31)]);
}

// ---- CSR build ----
__global__ void count_edges(const int* __restrict__ edst, int* __restrict__ counts) {
    int t = blockIdx.x * 256 + threadIdx.x;
    if (t < EDG_N) atomicAdd(&counts[edst[t]], 1);
}

__global__ void scan_block(const int* __restrict__ counts, int* __restrict__ partial,
                           int* __restrict__ chunk) {
    __shared__ int sh[512];
    int i = blockIdx.x * 512 + threadIdx.x;
    int v = (i < NS_N) ? counts[i] : 0;
    sh[threadIdx.x] = v;
    __syncthreads();
    for (int off = 1; off < 512; off <<= 1) {
        int x = (threadIdx.x >= off) ? sh[threadIdx.x - off] : 0;
        __syncthreads();
        sh[threadIdx.x] += x;
        __syncthreads();
    }
    if (i < NS_N) partial[i] = sh[threadIdx.x] - v;  // exclusive
    if (threadIdx.x == 511) chunk[blockIdx.x] = sh[511];
}

__global__ void scan_chunks(int* __restrict__ chunk, int nc) {
    __shared__ int sh[256];
    int t = threadIdx.x;
    int v = (t < nc) ? chunk[t] : 0;
    sh[t] = v;
    __syncthreads();
    for (int off = 1; off < 256; off <<= 1) {
        int x = (t >= off) ? sh[t - off] : 0;
        __syncthreads();
        sh[t] += x;
        __syncthreads();
    }
    if (t < nc) chunk[t] = sh[t] - v;  // exclusive
}

__global__ void add_offsets(int* __restrict__ rowst, const int* __restrict__ chunk,
                            int* __restrict__ cursor) {
    int i = blockIdx.x * 256 + threadIdx.x;
    if (i < NS_N) {
        int r = rowst[i] + chunk[i >> 9];
        rowst[i] = r;
        cursor[i] = r;
    }
}

__global__ void scatter_edges(const int* __restrict__ esrc, const int* __restrict__ edst,
                              int* __restrict__ cursor, int* __restrict__ csr) {
    int t = blockIdx.x * 256 + threadIdx.x;
    if (t < EDG_N) {
        int d = edst[t];
        int pos = atomicAdd(&cursor[d], 1);
        csr[pos] = esrc[t];
    }
}

// ---- Weight-stationary streaming MFMA GEMM ----
// C[M,N] = epi(A[M,K] @ BT[N,K]^T + bias) (+ res)
// 512-thread blocks (8 waves). Each wave holds its 32-col B-slice IN REGISTERS
// for the whole kernel (breg[K/32][2], loaded once -> loop-invariant, cannot be
// sunk into the row loop). A is streamed in BR-row chunks through double-
// buffered LDS via global_load_lds (no VGPR round-trip), counted vmcnt + raw
// s_barrier (never vmcnt(0) mid-loop). Compute phase is pure LDS+MFMA.
// XOR 16B-slot swizzle on A (pre-swizzled source / swizzled read). Swapped
// MFMA operands -> lane owns (row, 4 consecutive cols) -> vector epilogue.
// CG column groups for N=512 (each block covers 256 cols).
template <int BR, int K, int N, class TC, bool BIAS, bool GELU, bool RES>
__global__ __launch_bounds__(512, 2) void mfma_gemm6(
    const bf16* __restrict__ A, const bf16* __restrict__ BT,
    const float* __restrict__ bias, const float* __restrict__ res,
    TC* __restrict__ C, int M, int nchunks, int nblk) {
    static_assert(K % 64 == 0 && (N == 256 || N == 512) && (BR == 32 || BR == 64), "shape");
    constexpr int KS = K / 32;                 // k-steps
    constexpr int MT = BR / 16;                // row tiles per wave
    constexpr int W = BR * K / 4096;           // g2l16 per wave per chunk (1 or 4)
    constexpr int WROWS = BR / 8;              // rows staged per wave
    __shared__ bf16 As[2][BR * K];

    const int tid = threadIdx.x;
    const int wave = tid >> 6, lane = tid & 63;
    const int cg = blockIdx.x / nblk;          // column group (N=512 -> 2)
    const int blk = blockIdx.x - cg * nblk;
    const int cb = cg * 256 + wave * 32;
    const int fr = lane & 15, q = lane >> 4;
    const int f7 = fr & 7;
    const int q4 = q * 4;

    // ---- B-slice into registers, ONCE ----
    bf16x8 breg[KS][2];
#pragma unroll
    for (int ks = 0; ks < KS; ++ks) {
        breg[ks][0] = *(const bf16x8*)(BT + (size_t)(cb + fr) * K + ks * 32 + q * 8);
        breg[ks][1] = *(const bf16x8*)(BT + (size_t)(cb + 16 + fr) * K + ks * 32 + q * 8);
    }

    auto STAGE = [&](int chunk, int buf) {
#pragma unroll
        for (int ci = 0; ci < W; ++ci) {
            int off = ci * 1024 + lane * 16;       // byte offset within wave's panel
            int riw = off / (K * 2);               // row within wave's WROWS
            int slot = (off % (K * 2)) / 16;       // phys 16B slot within row
            int row = wave * WROWS + riw;
            const bf16* g = A + (size_t)(chunk * BR + row) * K + (slot ^ (row & 7)) * 8;
            g2l16(g, &As[buf][(size_t)(wave * WROWS) * K + ci * 512]);
        }
    };

    int c = blk;
    STAGE(c, 0);   // every block has >=1 chunk (nblk <= nchunks)
    int buf = 0;
    for (; c < nchunks; c += nblk) {
        const int cn = c + nblk;
        if (cn < nchunks) {
            STAGE(cn, buf ^ 1);
            if constexpr (W == 1) asm volatile("s_waitcnt vmcnt(1)" ::: "memory");
            else                  asm volatile("s_waitcnt vmcnt(4)" ::: "memory");
        } else {
            asm volatile("s_waitcnt vmcnt(0)" ::: "memory");
        }
        __builtin_amdgcn_s_barrier();
        asm volatile("" ::: "memory");

        const bf16* Ab = As[buf];
        f32x4 acc[MT][2];
        const f32x4 zero4 = {0.f, 0.f, 0.f, 0.f};
#pragma unroll
        for (int mt = 0; mt < MT; mt++) {
            acc[mt][0] = zero4;
            acc[mt][1] = zero4;
        }
#pragma unroll
        for (int ks = 0; ks < KS; ++ks) {
            const int slot = (ks * 4 + q) ^ f7;    // read-side swizzle (row&7 == fr&7)
#pragma unroll
            for (int mt = 0; mt < MT; mt++) {
                bf16x8 af = *(const bf16x8*)(Ab + (size_t)(mt * 16 + fr) * K + slot * 8);
                acc[mt][0] = __builtin_amdgcn_mfma_f32_16x16x32_bf16(breg[ks][0], af, acc[mt][0], 0, 0, 0);
                acc[mt][1] = __builtin_amdgcn_mfma_f32_16x16x32_bf16(breg[ks][1], af, acc[mt][1], 0, 0, 0);
            }
        }
        asm volatile("" ::: "memory");
        __builtin_amdgcn_s_barrier();   // all reads of buf done before it is restaged

        // ---- vector epilogue: lane owns row = m0+mt*16+fr, cols cb+jt*16+q4..+3
        const int m0 = c * BR;
#pragma unroll
        for (int jt = 0; jt < 2; jt++) {
            const int col = cb + jt * 16 + q4;
            float4 bv4 = {0.f, 0.f, 0.f, 0.f};
            if (BIAS) bv4 = *(const float4*)&bias[col];
#pragma unroll
            for (int mt = 0; mt < MT; mt++) {
                const int row = m0 + mt * 16 + fr;
                if (row < M) {
                    float v0 = acc[mt][jt][0] + bv4.x;
                    float v1 = acc[mt][jt][1] + bv4.y;
                    float v2 = acc[mt][jt][2] + bv4.z;
                    float v3 = acc[mt][jt][3] + bv4.w;
                    if (RES) {
                        float4 r4 = *(const float4*)&res[(size_t)row * N + col];
                        v0 += r4.x; v1 += r4.y; v2 += r4.z; v3 += r4.w;
                    }
                    if (GELU) {
                        float vv[4] = {v0, v1, v2, v3};
#pragma unroll
                        for (int r = 0; r < 4; r++) {
                            float x = vv[r];
                            float u = 0.7978845608028654f * (x + 0.044715f * x * x * x);
                            float eu = __expf(-2.f * fabsf(u));
                            float th = (1.f - eu) / (1.f + eu);
                            th = (u >= 0.f) ? th : -th;
                            vv[r] = 0.5f * x * (1.f + th);
                        }
                        v0 = vv[0]; v1 = vv[1]; v2 = vv[2]; v3 = vv[3];
                    }
                    if constexpr (sizeof(TC) == 4) {
                        float4 o = {v0, v1, v2, v3};
                        *(float4*)&C[(size_t)row * N + col] = o;
                    } else {
                        union { ushort4 u; bf16 h[4]; } o;
                        o.h[0] = fromF<bf16>(v0);
                        o.h[1] = fromF<bf16>(v1);
                        o.h[2] = fromF<bf16>(v2);
                        o.h[3] = fromF<bf16>(v3);
                        *(ushort4*)&C[(size_t)row * N + col] = o.u;
                    }
                }
            }
        }
        buf ^= 1;
    }
}

// ---- fused edge-softmax attention + elu ----
// ONE WAVE per dst (4 waves/block). lane holds 4 channels (bf16x4);
// head = 32ch = 8 lanes -> 3-step butterfly score reduce.
// csr indices prefetched 64-at-a-time into a register, broadcast by shfl.
// 4-edge batched online softmax: 4 gather rows in flight per wave.
__device__ __forceinline__ float4 ldz4(const bf16* __restrict__ p) {
    ushort4 u = *(const ushort4*)p;
    float4 f;
    f.x = toF(*(const bf16*)&u.x);
    f.y = toF(*(const bf16*)&u.y);
    f.z = toF(*(const bf16*)&u.z);
    f.w = toF(*(const bf16*)&u.w);
    return f;
}

__device__ __forceinline__ float dot4(float4 a, float4 b) {
    return fmaf(a.x, b.x, fmaf(a.y, b.y, fmaf(a.z, b.z, a.w * b.w)));
}

__device__ __forceinline__ float hred8(float p) {
    p += __shfl_xor(p, 1);
    p += __shfl_xor(p, 2);
    p += __shfl_xor(p, 4);
    return p;
}

__global__ __launch_bounds__(256) void attn_k(
    const bf16* __restrict__ z, const bf16* __restrict__ df,
    const int* __restrict__ rowst, const int* __restrict__ counts,
    const int* __restrict__ csr, bf16* __restrict__ he) {
    const int dst = blockIdx.x * 4 + (threadIdx.x >> 6);
    if (dst >= NS_N) return;
    const int lane = threadIdx.x & 63;
    const int c4 = lane * 4;  // channel base for this lane

    float4 dfv = ldz4(&df[(size_t)dst * DIM + c4]);

    const int rs = rowst[dst], deg = counts[dst];
    float m = -1e30f, l = 0.f;
    float4 acc = {0.f, 0.f, 0.f, 0.f};

    for (int c0 = 0; c0 < deg; c0 += 64) {
        const int nc = min(64, deg - c0);
        int idx = (lane < nc) ? csr[rs + c0 + lane] : 0;
        int j = 0;
        for (; j + 4 <= nc; j += 4) {
            int s0 = __shfl(idx, j);
            int s1 = __shfl(idx, j + 1);
            int s2 = __shfl(idx, j + 2);
            int s3 = __shfl(idx, j + 3);
            float4 z0 = ldz4(&z[(size_t)s0 * DIM + c4]);
            float4 z1 = ldz4(&z[(size_t)s1 * DIM + c4]);
            float4 z2 = ldz4(&z[(size_t)s2 * DIM + c4]);
            float4 z3 = ldz4(&z[(size_t)s3 * DIM + c4]);
            float p0 = hred8(dot4(z0, dfv));
            float p1 = hred8(dot4(z1, dfv));
            float p2 = hred8(dot4(z2, dfv));
            float p3 = hred8(dot4(z3, dfv));
            float nm = fmaxf(m, fmaxf(fmaxf(p0, p1), fmaxf(p2, p3)));
            float e0 = __expf(m - nm);
            float w0 = __expf(p0 - nm);
            float w1 = __expf(p1 - nm);
            float w2 = __expf(p2 - nm);
            float w3 = __expf(p3 - nm);
            l = fmaf(l, e0, (w0 + w1) + (w2 + w3));
            acc.x = fmaf(acc.x, e0, fmaf(w0, z0.x, fmaf(w1, z1.x, fmaf(w2, z2.x, w3 * z3.x))));
            acc.y = fmaf(acc.y, e0, fmaf(w0, z0.y, fmaf(w1, z1.y, fmaf(w2, z2.y, w3 * z3.y))));
            acc.z = fmaf(acc.z, e0, fmaf(w0, z0.z, fmaf(w1, z1.z, fmaf(w2, z2.z, w3 * z3.z))));
            acc.w = fmaf(acc.w, e0, fmaf(w0, z0.w, fmaf(w1, z1.w, fmaf(w2, z2.w, w3 * z3.w))));
            m = nm;
        }
        for (; j < nc; ++j) {
            int s0 = __shfl(idx, j);
            float4 z0 = ldz4(&z[(size_t)s0 * DIM + c4]);
            float p0 = hred8(dot4(z0, dfv));
            float nm = fmaxf(m, p0);
            float e0 = __expf(m - nm);
            float w0 = __expf(p0 - nm);
            l = fmaf(l, e0, w0);
            acc.x = fmaf(acc.x, e0, w0 * z0.x);
            acc.y = fmaf(acc.y, e0, w0 * z0.y);
            acc.z = fmaf(acc.z, e0, w0 * z0.z);
            acc.w = fmaf(acc.w, e0, w0 * z0.w);
            m = nm;
        }
    }

    const float invl = 1.f / l;
    float hx = acc.x * invl, hy = acc.y * invl, hz = acc.z * invl, hw = acc.w * invl;
    hx = (hx > 0.f) ? hx : expm1f(hx);
    hy = (hy > 0.f) ? hy : expm1f(hy);
    hz = (hz > 0.f) ? hz : expm1f(hz);
    hw = (hw > 0.f) ? hw : expm1f(hw);
    union { ushort4 u; bf16 h[4]; } o;
    o.h[0] = fromF<bf16>(hx);
    o.h[1] = fromF<bf16>(hy);
    o.h[2] = fromF<bf16>(hz);
    o.h[3] = fromF<bf16>(hw);
    *(ushort4*)&he[(size_t)dst * 512 + c4] = o.u;
}

// ---- layernorm over 256, write bf16 ----
__global__ __launch_bounds__(256) void ln_k(const float* __restrict__ h1,
                                            const float* __restrict__ g,
                                            const float* __restrict__ b,
                                            bf16* __restrict__ xn) {
    int row = blockIdx.x, t = threadIdx.x;
    float x = h1[(size_t)row * DIM + t];
    float s1 = x, s2 = x * x;
#pragma unroll
    for (int off = 32; off > 0; off >>= 1) {
        s1 += __shfl_xor(s1, off, 64);
        s2 += __shfl_xor(s2, off, 64);
    }
    __shared__ float red[2][4];
    int w = t >> 6;
    if ((t & 63) == 0) {
        red[0][w] = s1;
        red[1][w] = s2;
    }
    __syncthreads();
    float t1 = red[0][0] + red[0][1] + red[0][2] + red[0][3];
    float t2 = red[1][0] + red[1][1] + red[1][2] + red[1][3];
    float mu = t1 * (1.f / DIM);
    float var = t2 * (1.f / DIM) - mu * mu;
    float v = (x - mu) * rsqrtf(var + 1e-6f) * g[t] + b[t];
    xn[(size_t)row * DIM + t] = fromF<bf16>(v);
}

extern "C" void kernel_launch(void* const* d_in, const int* in_sizes, int n_in,
                              void* d_out, int out_size, void* d_ws, size_t ws_size,
                              hipStream_t stream) {
    const float* s = (const float*)d_in[0];
    const float* e = (const float*)d_in[1];
    const float* dst_feat = (const float*)d_in[2];
    const float* fc_w = (const float*)d_in[3];
    const float* dstfeat_w = (const float*)d_in[4];
    const float* proj_w = (const float*)d_in[5];
    const float* proj_b = (const float*)d_in[6];
    const float* ln_g = (const float*)d_in[7];
    const float* ln_b = (const float*)d_in[8];
    const float* w1 = (const float*)d_in[9];
    const float* b1 = (const float*)d_in[10];
    const float* w2 = (const float*)d_in[11];
    const float* b2 = (const float*)d_in[12];
    const int* edge_src = (const int*)d_in[13];
    const int* edge_dst = (const int*)d_in[14];
    float* out = (float*)d_out;

    char* base = (char*)d_ws;
    size_t off = 0;
    auto alloc = [&](size_t bytes) -> char* {
        char* p = base + off;
        off = (off + bytes + 255) & ~(size_t)255;
        return p;
    };
    // bf16 transposed weights [N][K]
    bf16* fcT = (bf16*)alloc((size_t)256 * 256 * 2);
    bf16* dfeatT = (bf16*)alloc((size_t)256 * 64 * 2);
    bf16* projT = (bf16*)alloc((size_t)256 * 512 * 2);
    bf16* w1T = (bf16*)alloc((size_t)512 * 256 * 2);
    bf16* w2T = (bf16*)alloc((size_t)256 * 512 * 2);
    int* counts = (int*)alloc((size_t)NS_N * 4);
    int* rowst = (int*)alloc((size_t)NS_N * 4);
    int* cursor = (int*)alloc((size_t)NS_N * 4);
    int* chunks = (int*)alloc(1024);
    int* csr = (int*)alloc((size_t)EDG_N * 4);
    bf16* eB = (bf16*)alloc((size_t)MP * DIM * 2);      // 51.2 MB; reused as xnB
    bf16* zB = (bf16*)alloc((size_t)MP * DIM * 2);      // 51.2 MB \ contiguous ->
    bf16* dfB = (bf16*)alloc((size_t)MP * DIM * 2);     // 51.2 MB / a1B (MP x 512)
    bf16* dfeatB = (bf16*)alloc((size_t)MP * FEAT_N * 2);
    bf16* catB = (bf16*)alloc((size_t)MP * 512 * 2);    // [he | s]
    float* h1F = (float*)alloc((size_t)MP * DIM * 4);
    bf16* xnB = eB;   // e dead after gemm1
    bf16* a1B = zB;   // z,df dead after attn; spans zB+dfB = MP*512 bf16

    hipMemsetAsync(counts, 0, (size_t)NS_N * 4, stream);
    // weight prep
    tr_headw<<<(256 * 256 + 255) / 256, 256, 0, stream>>>(fc_w, fcT, 256);
    tr_headw<<<(256 * 64 + 255) / 256, 256, 0, stream>>>(dstfeat_w, dfeatT, 64);
    tr_w<<<(512 * 256 + 255) / 256, 256, 0, stream>>>(proj_w, projT, 512, 256);
    tr_w<<<(256 * 512 + 255) / 256, 256, 0, stream>>>(w1, w1T, 256, 512);
    tr_w<<<(512 * 256 + 255) / 256, 256, 0, stream>>>(w2, w2T, 512, 256);
    // activation converts
    cvt_f2b4<<<(NE_N * 64 + 255) / 256, 256, 0, stream>>>((const float4*)e, eB, NE_N, 64, DIM);
    cvt_f2b4<<<(NS_N * 16 + 255) / 256, 256, 0, stream>>>((const float4*)dst_feat, dfeatB, NS_N, 16, FEAT_N);
    cvt_f2b4<<<(NS_N * 64 + 255) / 256, 256, 0, stream>>>((const float4*)s, catB + 256, NS_N, 64, 512);
    // CSR
    count_edges<<<(EDG_N + 255) / 256, 256, 0, stream>>>(edge_dst, counts);
    int nchunk = (NS_N + 511) / 512;
    scan_block<<<nchunk, 512, 0, stream>>>(counts, rowst, chunks);
    scan_chunks<<<1, 256, 0, stream>>>(chunks, nchunk);
    add_offsets<<<(NS_N + 255) / 256, 256, 0, stream>>>(rowst, chunks, cursor);
    scatter_edges<<<(EDG_N + 255) / 256, 256, 0, stream>>>(edge_src, edge_dst, cursor, csr);

    dim3 blk(512);
    const int NB = 512;               // row-blocks for K<=256 kernels
    // z = e @ Wz -> bf16   (BR=64, 1564 chunks)
    mfma_gemm6<64, 256, 256, bf16, false, false, false><<<NB, blk, 0, stream>>>(
        eB, fcT, nullptr, nullptr, zB, NE_N, MP / 64, NB);
    // df = dst_feat @ Wd -> bf16
    mfma_gemm6<64, 64, 256, bf16, false, false, false><<<NB, blk, 0, stream>>>(
        dfeatB, dfeatT, nullptr, nullptr, dfB, NS_N, MP / 64, NB);
    // attention -> catB left half (one wave per dst, 4 dsts per block)
    attn_k<<<(NS_N + 3) / 4, 256, 0, stream>>>(zB, dfB, rowst, counts, csr, catB);
    // h1 = cat(he,s) @ proj_w + proj_b -> fp32   (K=512: BR=32, 3128 chunks)
    mfma_gemm6<32, 512, 256, float, true, false, false><<<NB, blk, 0, stream>>>(
        catB, projT, proj_b, nullptr, h1F, NS_N, MP / 32, NB);
    // xn = LN(h1) -> bf16
    ln_k<<<NS_N, 256, 0, stream>>>(h1F, ln_g, ln_b, xnB);
    // a1 = gelu(xn @ w1 + b1) -> bf16  (N=512: 2 column groups)
    mfma_gemm6<64, 256, 512, bf16, true, true, false><<<2 * NB, blk, 0, stream>>>(
        xnB, w1T, b1, nullptr, a1B, NS_N, MP / 64, NB);
    // out = h1 + (a1 @ w2 + b2) -> fp32  (K=512: BR=32)
    mfma_gemm6<32, 512, 256, float, true, false, true><<<NB, blk, 0, stream>>>(
        a1B, w2T, b2, h1F, out, NS_N, MP / 32, NB);
}